// Round 5
// baseline (160.311 us; speedup 1.0000x reference)
//
#include <hip/hip_runtime.h>

// 2-layer GCN collapsed to scalar per-node quantities (verified R2):
//   dis = 1/sqrt(deg+1);  y = x*dis;  t[d] = sum_{e->d} y[src]
//   s = dis*(t+y);  z = dis * sum_j relu(s*W1[j]+b1[j])*W2[j]
//   out[d] = dis[d]*(sum_{e->d} z[src] + z[d]) + b2
//
// R17: agg passes were parallelism-capped: 196 blocks x 16 waves = 77% CU
// coverage, 16/32 wave slots, no 2nd block. Split each bucket's 16 sets
// across 2 blocks of 8 waves (grid 392 x 512): all 256 CUs busy. Cross-block
// combine via ~200K spread device atomics/pass (2 per address — 1/100th of
// R14's contention) + R14-proven claim (vmcnt drain + agent loads). Epilogue
// runs in the 2nd-finishing block. part_k byte-identical to R16.

#define SB_BITS 9
#define SBK     512           // nodes per bucket
#define MAXB    256           // histogram size == TBP (1 bucket/thread)
#define TBP     256           // part_k block size
#define NAPB    1024          // part_k grid (64 blocks per set)
#define TPT     4096          // part_k tile (16 edges/thread)
#define KPT     16
#define NW      4             // waves per part_k block
#define NSET    16            // independent cursor/region sets
#define GSTRIDE 8             // u32 stride between cursors (32B granule)
#define NSPLIT  2             // agg blocks per bucket
#define SPS     8             // sets per agg block (NSET/NSPLIT)
#define TBA     512           // aggregation block size (8 waves = 8 sets)

__device__ inline void lds_addf(float* p, float v) {
    __hip_atomic_fetch_add(p, v, __ATOMIC_RELAXED, __HIP_MEMORY_SCOPE_WORKGROUP);
}

__device__ inline unsigned agent_ld_u(const unsigned* p) {
    return __hip_atomic_load(p, __ATOMIC_RELAXED, __HIP_MEMORY_SCOPE_AGENT);
}
__device__ inline float agent_ld_f(const float* p) {
    return __hip_atomic_load(p, __ATOMIC_RELAXED, __HIP_MEMORY_SCOPE_AGENT);
}

// last-of-NSPLIT claim. vmcnt drain before the counter bump makes this
// block's device-scope atomics globally performed first (R14-proven).
__device__ inline int claim_last(unsigned* c) {
    __shared__ int lastf;
    asm volatile("s_waitcnt vmcnt(0)" ::: "memory");
    __syncthreads();
    if (threadIdx.x == 0)
        lastf = (atomicAdd(c, 1u) == NSPLIT - 1u);
    __syncthreads();
    return lastf;
}

// ---------------- K1: partition ----------------
__global__ __launch_bounds__(TBP) void part_k(
        const int* __restrict__ src, const int* __restrict__ dst, int E,
        int cap, int capS, unsigned* __restrict__ gcur,
        unsigned* __restrict__ packedB) {
    __shared__ unsigned sp[TPT];
    __shared__ unsigned char sbk[TPT];
    __shared__ unsigned woff[NW][MAXB];
    __shared__ unsigned cnt2[NW][MAXB];
    __shared__ unsigned scn[MAXB];
    __shared__ unsigned gbase[MAXB];
    __shared__ unsigned wtot[NW];
    const int t = threadIdx.x;
    const int w = t >> 6;
    const int lane = t & 63;
    const int set = blockIdx.x & (NSET - 1);
    int CH = (E + (int)gridDim.x - 1) / (int)gridDim.x;
    int cs = blockIdx.x * CH;
    int ce = min(cs + CH, E);
    for (int ts = cs; ts < ce; ts += TPT) {
        int tcnt = min(TPT, ce - ts);
        // zero histograms (MAXB == TBP: one bucket per thread)
        #pragma unroll
        for (int ww = 0; ww < NW; ww++) { woff[ww][t] = 0u; cnt2[ww][t] = 0u; }
        __syncthreads();
        unsigned es[KPT], ed[KPT]; int nk = 0;
        #pragma unroll
        for (int k = 0; k < KPT; k++) {
            int j = ts + t + k * TBP;
            if (j < ce) {
                es[k] = (unsigned)src[j];
                ed[k] = (unsigned)dst[j];
                atomicAdd(&woff[w][ed[k] >> SB_BITS], 1u);
                nk = k + 1;
            }
        }
        __syncthreads();
        // per-bucket totals -> wave offsets, global cursor, block-wide scan
        unsigned h0 = woff[0][t], h1 = woff[1][t], h2 = woff[2][t], h3 = woff[3][t];
        woff[0][t] = 0u; woff[1][t] = h0; woff[2][t] = h0 + h1;
        woff[3][t] = h0 + h1 + h2;
        unsigned th = h0 + h1 + h2 + h3;
        gbase[t] = th ? atomicAdd(&gcur[(t * NSET + set) * GSTRIDE], th) : 0u;
        unsigned v = th;
        #pragma unroll
        for (int off = 1; off < 64; off <<= 1) {
            unsigned u = __shfl_up(v, off, 64);
            if (lane >= off) v += u;
        }
        if (lane == 63) wtot[w] = v;
        __syncthreads();
        unsigned wpre = 0;
        #pragma unroll
        for (int ww = 0; ww < NW; ww++) wpre += (ww < w) ? wtot[ww] : 0u;
        scn[t] = wpre + v - th;        // block-exclusive base for bucket t
        __syncthreads();
        for (int k = 0; k < nk; k++) {
            unsigned b = ed[k] >> SB_BITS;
            unsigned r = scn[b] + woff[w][b] + atomicAdd(&cnt2[w][b], 1u);
            sp[r]  = es[k] | ((ed[k] & (SBK - 1u)) << 17);
            sbk[r] = (unsigned char)b;
        }
        __syncthreads();
        #pragma unroll
        for (int k = 0; k < KPT; k++) {
            int j2 = t + k * TBP;
            if (j2 < tcnt) {
                unsigned b = sbk[j2];
                unsigned gpos = gbase[b] + (unsigned)j2 - scn[b];
                if (gpos < (unsigned)capS)
                    packedB[(size_t)b * cap + (size_t)set * capS + gpos] = sp[j2];
            }
        }
        __syncthreads();
    }
}

// ---------------- K2: degree (split) + prep1 (dis, y) ----------------
__global__ __launch_bounds__(TBA) void degp_k(
        const unsigned* __restrict__ packedB, const unsigned* __restrict__ gcur,
        int cap, int capS, unsigned* __restrict__ tdeg,
        unsigned* __restrict__ ctr, const float* __restrict__ x, int N,
        float* __restrict__ dis, float* __restrict__ y) {
    __shared__ unsigned acc[SBK];
    acc[threadIdx.x] = 0u;           // TBA == SBK
    __syncthreads();
    const int b = blockIdx.x >> 1;
    const int h = blockIdx.x & 1;
    const int w = threadIdx.x >> 6;
    const int lane = threadIdx.x & 63;
    const int set = h * SPS + w;     // wave = one set
    unsigned cnt = min(gcur[(b * NSET + set) * GSTRIDE], (unsigned)capS);
    const unsigned* p = packedB + (size_t)b * cap + (size_t)set * capS;
    const uint4* p4 = (const uint4*)p;
    unsigned nq = cnt >> 2;
    unsigned qi = lane;
    for (; qi + 64 < nq; qi += 128) {
        uint4 a = p4[qi], c = p4[qi + 64];
        atomicAdd(&acc[a.x >> 17], 1u); atomicAdd(&acc[a.y >> 17], 1u);
        atomicAdd(&acc[a.z >> 17], 1u); atomicAdd(&acc[a.w >> 17], 1u);
        atomicAdd(&acc[c.x >> 17], 1u); atomicAdd(&acc[c.y >> 17], 1u);
        atomicAdd(&acc[c.z >> 17], 1u); atomicAdd(&acc[c.w >> 17], 1u);
    }
    for (; qi < nq; qi += 64) {
        uint4 a = p4[qi];
        atomicAdd(&acc[a.x >> 17], 1u); atomicAdd(&acc[a.y >> 17], 1u);
        atomicAdd(&acc[a.z >> 17], 1u); atomicAdd(&acc[a.w >> 17], 1u);
    }
    for (unsigned j = (nq << 2) + lane; j < cnt; j += 64)
        atomicAdd(&acc[p[j] >> 17], 1u);
    __syncthreads();
    const int base = b << SB_BITS;
    unsigned v = acc[threadIdx.x];
    if (v) atomicAdd(&tdeg[base + threadIdx.x], v);   // spread: 2 adds/address

    if (!claim_last(&ctr[b])) return;
    int gi = base + threadIdx.x;
    if (gi < N) {
        unsigned d = 1u + agent_ld_u(&tdeg[gi]);      // +1 self loop
        float rr = 1.0f / sqrtf((float)d);
        dis[gi] = rr;
        y[gi] = x[gi] * rr;
    }
}

// ---------------- K3: gather y (split) + prep2 (z) ----------------
__global__ __launch_bounds__(TBA) void gacc1_k(
        const unsigned* __restrict__ packedB, const unsigned* __restrict__ gcur,
        const float* __restrict__ val /* y */, int cap, int capS,
        float* __restrict__ tsum, unsigned* __restrict__ ctr,
        const float* __restrict__ dis,
        const float* __restrict__ W1, const float* __restrict__ b1,
        const float* __restrict__ W2, float* __restrict__ z, int N) {
    __shared__ float acc[SBK];
    __shared__ float sW1[256], sb1[256], sW2[256];
    acc[threadIdx.x] = 0.0f;         // TBA == SBK
    __syncthreads();
    const int b = blockIdx.x >> 1;
    const int h = blockIdx.x & 1;
    const int w = threadIdx.x >> 6;
    const int lane = threadIdx.x & 63;
    const int set = h * SPS + w;
    unsigned cnt = min(gcur[(b * NSET + set) * GSTRIDE], (unsigned)capS);
    const unsigned* p = packedB + (size_t)b * cap + (size_t)set * capS;
    const uint4* p4 = (const uint4*)p;
    unsigned nq = cnt >> 2;
    unsigned qi = lane;
    for (; qi + 64 < nq; qi += 128) {
        uint4 a = p4[qi], c = p4[qi + 64];
        float v0 = val[a.x & 0x1FFFFu], v1 = val[a.y & 0x1FFFFu];
        float v2 = val[a.z & 0x1FFFFu], v3 = val[a.w & 0x1FFFFu];
        float v4 = val[c.x & 0x1FFFFu], v5 = val[c.y & 0x1FFFFu];
        float v6 = val[c.z & 0x1FFFFu], v7 = val[c.w & 0x1FFFFu];
        lds_addf(&acc[a.x >> 17], v0); lds_addf(&acc[a.y >> 17], v1);
        lds_addf(&acc[a.z >> 17], v2); lds_addf(&acc[a.w >> 17], v3);
        lds_addf(&acc[c.x >> 17], v4); lds_addf(&acc[c.y >> 17], v5);
        lds_addf(&acc[c.z >> 17], v6); lds_addf(&acc[c.w >> 17], v7);
    }
    for (; qi < nq; qi += 64) {
        uint4 a = p4[qi];
        float v0 = val[a.x & 0x1FFFFu], v1 = val[a.y & 0x1FFFFu];
        float v2 = val[a.z & 0x1FFFFu], v3 = val[a.w & 0x1FFFFu];
        lds_addf(&acc[a.x >> 17], v0); lds_addf(&acc[a.y >> 17], v1);
        lds_addf(&acc[a.z >> 17], v2); lds_addf(&acc[a.w >> 17], v3);
    }
    for (unsigned j = (nq << 2) + lane; j < cnt; j += 64) {
        unsigned pk = p[j];
        lds_addf(&acc[pk >> 17], val[pk & 0x1FFFFu]);
    }
    __syncthreads();
    const int base = b << SB_BITS;
    float fv = acc[threadIdx.x];
    if (fv != 0.0f) atomicAdd(&tsum[base + threadIdx.x], fv);

    if (!claim_last(&ctr[b])) return;
    if (threadIdx.x < 256) {
        sW1[threadIdx.x] = W1[threadIdx.x];
        sb1[threadIdx.x] = b1[threadIdx.x];
        sW2[threadIdx.x] = W2[threadIdx.x];
    }
    __syncthreads();
    const float4* w1v = (const float4*)sW1;
    const float4* b1v = (const float4*)sb1;
    const float4* w2v = (const float4*)sW2;
    int gi = base + threadIdx.x;
    if (gi < N) {
        float tt = agent_ld_f(&tsum[gi]);
        float rr = dis[gi];
        float s = rr * (tt + val[gi]);
        float g = 0.0f;
        #pragma unroll 8
        for (int jj = 0; jj < 64; jj++) {   // H=256 -> 64 quads
            float4 a = w1v[jj], bb = b1v[jj], c = w2v[jj];
            float h0 = fmaf(s, a.x, bb.x); h0 = h0 > 0.0f ? h0 : 0.0f;
            float h1 = fmaf(s, a.y, bb.y); h1 = h1 > 0.0f ? h1 : 0.0f;
            float h2 = fmaf(s, a.z, bb.z); h2 = h2 > 0.0f ? h2 : 0.0f;
            float h3 = fmaf(s, a.w, bb.w); h3 = h3 > 0.0f ? h3 : 0.0f;
            g = fmaf(h0, c.x, g); g = fmaf(h1, c.y, g);
            g = fmaf(h2, c.z, g); g = fmaf(h3, c.w, g);
        }
        z[gi] = g * rr;
    }
}

// ---------------- K4: gather z (split) + finout ----------------
__global__ __launch_bounds__(TBA) void gacc2_k(
        const unsigned* __restrict__ packedB, const unsigned* __restrict__ gcur,
        const float* __restrict__ val /* z */, int cap, int capS,
        float* __restrict__ tsum, unsigned* __restrict__ ctr,
        const float* __restrict__ dis, const float* __restrict__ b2,
        float* __restrict__ out, int N) {
    __shared__ float acc[SBK];
    acc[threadIdx.x] = 0.0f;         // TBA == SBK
    __syncthreads();
    const int b = blockIdx.x >> 1;
    const int h = blockIdx.x & 1;
    const int w = threadIdx.x >> 6;
    const int lane = threadIdx.x & 63;
    const int set = h * SPS + w;
    unsigned cnt = min(gcur[(b * NSET + set) * GSTRIDE], (unsigned)capS);
    const unsigned* p = packedB + (size_t)b * cap + (size_t)set * capS;
    const uint4* p4 = (const uint4*)p;
    unsigned nq = cnt >> 2;
    unsigned qi = lane;
    for (; qi + 64 < nq; qi += 128) {
        uint4 a = p4[qi], c = p4[qi + 64];
        float v0 = val[a.x & 0x1FFFFu], v1 = val[a.y & 0x1FFFFu];
        float v2 = val[a.z & 0x1FFFFu], v3 = val[a.w & 0x1FFFFu];
        float v4 = val[c.x & 0x1FFFFu], v5 = val[c.y & 0x1FFFFu];
        float v6 = val[c.z & 0x1FFFFu], v7 = val[c.w & 0x1FFFFu];
        lds_addf(&acc[a.x >> 17], v0); lds_addf(&acc[a.y >> 17], v1);
        lds_addf(&acc[a.z >> 17], v2); lds_addf(&acc[a.w >> 17], v3);
        lds_addf(&acc[c.x >> 17], v4); lds_addf(&acc[c.y >> 17], v5);
        lds_addf(&acc[c.z >> 17], v6); lds_addf(&acc[c.w >> 17], v7);
    }
    for (; qi < nq; qi += 64) {
        uint4 a = p4[qi];
        float v0 = val[a.x & 0x1FFFFu], v1 = val[a.y & 0x1FFFFu];
        float v2 = val[a.z & 0x1FFFFu], v3 = val[a.w & 0x1FFFFu];
        lds_addf(&acc[a.x >> 17], v0); lds_addf(&acc[a.y >> 17], v1);
        lds_addf(&acc[a.z >> 17], v2); lds_addf(&acc[a.w >> 17], v3);
    }
    for (unsigned j = (nq << 2) + lane; j < cnt; j += 64) {
        unsigned pk = p[j];
        lds_addf(&acc[pk >> 17], val[pk & 0x1FFFFu]);
    }
    __syncthreads();
    const int base = b << SB_BITS;
    float fv = acc[threadIdx.x];
    if (fv != 0.0f) atomicAdd(&tsum[base + threadIdx.x], fv);

    if (!claim_last(&ctr[b])) return;
    float bb2 = b2[0];
    int gi = base + threadIdx.x;
    if (gi < N) {
        float u = agent_ld_f(&tsum[gi]);
        out[gi] = dis[gi] * (u + val[gi]) + bb2;
    }
}

extern "C" void kernel_launch(void* const* d_in, const int* in_sizes, int n_in,
                              void* d_out, int out_size, void* d_ws, size_t ws_size,
                              hipStream_t stream) {
    const float* x   = (const float*)d_in[0];
    const int*   ei  = (const int*)d_in[1];     // int32 (JAX x64-off)
    const float* W1  = (const float*)d_in[2];
    const float* b1  = (const float*)d_in[3];
    const float* W2  = (const float*)d_in[4];
    const float* b2  = (const float*)d_in[5];
    float*       out = (float*)d_out;

    const int N = in_sizes[0];        // 100000
    const int E = in_sizes[1] / 2;    // 3200000

    const int* srcp = ei;
    const int* dstp = ei + E;

    const int NB   = (N + SBK - 1) >> SB_BITS;            // 196
    const int PLN  = NB * SBK;                            // 100352
    const int capS = (E / (NB * NSET) + 384 + 7) & ~7;    // ~12 sigma slack
    const int cap  = capS * NSET;
    const int NCUR = NB * NSET * GSTRIDE;                 // 25088 u32

    // workspace (u32 units), zero-init prefix:
    // [gcur NCUR][ctr 1024][tdeg PLN][ty PLN][tz PLN] | [dis N][y N][z N][packedB]
    unsigned* W    = (unsigned*)d_ws;
    unsigned* gcur = W;
    unsigned* ctr  = W + (size_t)NCUR;                    // 3 stages x 256
    unsigned* tdeg = W + (size_t)NCUR + 1024;
    float*    ty   = (float*)(tdeg + (size_t)PLN);
    float*    tz   = (float*)(tdeg + (size_t)2 * PLN);
    float*    dis  = (float*)(tdeg + (size_t)3 * PLN);
    float*    y    = (float*)(tdeg + (size_t)3 * PLN + (size_t)N);
    float*    z    = (float*)(tdeg + (size_t)3 * PLN + (size_t)2 * N);
    unsigned* packedB = tdeg + (size_t)3 * PLN + (size_t)3 * N;

    hipMemsetAsync(gcur, 0, ((size_t)NCUR + 1024 + (size_t)3 * PLN) * sizeof(unsigned),
                   stream);

    const int gA = NB * NSPLIT;   // 392

    part_k <<<NAPB, TBP, 0, stream>>>(srcp, dstp, E, cap, capS, gcur, packedB);
    degp_k <<<gA, TBA, 0, stream>>>(packedB, gcur, cap, capS, tdeg,
                                    ctr, x, N, dis, y);
    gacc1_k<<<gA, TBA, 0, stream>>>(packedB, gcur, y, cap, capS,
                                    ty, ctr + 256, dis, W1, b1, W2, z, N);
    gacc2_k<<<gA, TBA, 0, stream>>>(packedB, gcur, z, cap, capS,
                                    tz, ctr + 512, dis, b2, out, N);
}